// Round 7
// baseline (440.146 us; speedup 1.0000x reference)
//
#include <hip/hip_runtime.h>
#include <hip/hip_bf16.h>

#define B_ 4
#define S_ 2048
#define E_ 1024
#define H_ 8
#define D_ 128

using f16x8 = __attribute__((ext_vector_type(8))) _Float16;
using f32x4 = __attribute__((ext_vector_type(4))) float;

__device__ __forceinline__ ushort f2h_bits(float f) {
    union { _Float16 h; ushort u; } cv; cv.h = (_Float16)f; return cv.u;
}
__device__ __forceinline__ f16x8 pack8(const float* __restrict__ p) {
    float4 f0 = *(const float4*)p;
    float4 f1 = *(const float4*)(p + 4);
    f16x8 r;
    r[0] = (_Float16)f0.x; r[1] = (_Float16)f0.y;
    r[2] = (_Float16)f0.z; r[3] = (_Float16)f0.w;
    r[4] = (_Float16)f1.x; r[5] = (_Float16)f1.y;
    r[6] = (_Float16)f1.z; r[7] = (_Float16)f1.w;
    return r;
}

// ---------------- K/V projection ----------------
// BM=64: grid (B*S/64, H) = 1024 blocks (4/CU), 4 waves × 16 rows.
// K out: [B,H,S,D] fp16. V out TRANSPOSED: [B,H,D,S] fp16.
// Single 18.4KB LDS buffer reused K-pass then V-pass.
__global__ __launch_bounds__(256, 4) void kv_proj(
    const float* __restrict__ seq,
    const float* __restrict__ Wk, const float* __restrict__ Wv,
    const float* __restrict__ bk, const float* __restrict__ bv,
    ushort* __restrict__ ko, ushort* __restrict__ vo)
{
    __shared__ alignas(16) ushort T[128 * 72];   // 18432 B (K-pass uses [64][136]=8704)
    const int m0 = blockIdx.x * 64, h = blockIdx.y;
    const int tid = threadIdx.x, lane = tid & 63, w = tid >> 6;
    const int l16 = lane & 15, quad = lane >> 4;
    const int bi = m0 >> 11, sbase = m0 & (S_ - 1);   // 64-tile never crosses batch

    // A-frags: A[m=lane&15][k=quad*8+j], rows w*16..w*16+15
    f16x8 a[4];
    #pragma unroll
    for (int ks = 0; ks < 4; ++ks)
        a[ks] = pack8(&seq[(size_t)(m0 + w * 16 + l16) * E_ + h * D_ + ks * 32 + quad * 8]);

    // ---- K pass ----
    {
        const float* W = Wk + (size_t)h * D_ * D_;
        f32x4 acc[8];
        #pragma unroll
        for (int nt = 0; nt < 8; ++nt) { f32x4 z = {0.f,0.f,0.f,0.f}; acc[nt] = z; }
        #pragma unroll
        for (int ks = 0; ks < 4; ++ks)
            #pragma unroll
            for (int nt = 0; nt < 8; ++nt) {
                f16x8 bfr = pack8(&W[(size_t)(nt * 16 + l16) * D_ + ks * 32 + quad * 8]);
                acc[nt] = __builtin_amdgcn_mfma_f32_16x16x32_f16(a[ks], bfr, acc[nt], 0, 0, 0);
            }
        #pragma unroll
        for (int nt = 0; nt < 8; ++nt) {
            int o = nt * 16 + l16;
            float bias = bk[h * D_ + o];
            #pragma unroll
            for (int r = 0; r < 4; ++r) {
                int row = w * 16 + quad * 4 + r;
                T[row * 136 + (o ^ (quad << 3))] = f2h_bits(acc[nt][r] + bias);
            }
        }
    }
    __syncthreads();
    #pragma unroll
    for (int i = 0; i < 4; ++i) {
        int idx = tid + i * 256;
        int row = idx >> 4, c8 = (idx & 15) * 8;
        uint4 dk = *(uint4*)&T[row * 136 + (c8 ^ (((row >> 2) & 3) << 3))];
        *(uint4*)&ko[(((size_t)bi * H_ + h) * S_ + sbase + row) * D_ + c8] = dk;
    }
    __syncthreads();
    // ---- V pass (transposed into [d][s_local]) ----
    {
        const float* W = Wv + (size_t)h * D_ * D_;
        f32x4 acc[8];
        #pragma unroll
        for (int nt = 0; nt < 8; ++nt) { f32x4 z = {0.f,0.f,0.f,0.f}; acc[nt] = z; }
        #pragma unroll
        for (int ks = 0; ks < 4; ++ks)
            #pragma unroll
            for (int nt = 0; nt < 8; ++nt) {
                f16x8 bfr = pack8(&W[(size_t)(nt * 16 + l16) * D_ + ks * 32 + quad * 8]);
                acc[nt] = __builtin_amdgcn_mfma_f32_16x16x32_f16(a[ks], bfr, acc[nt], 0, 0, 0);
            }
        #pragma unroll
        for (int nt = 0; nt < 8; ++nt) {
            int o = nt * 16 + l16;
            float bias = bv[h * D_ + o];
            #pragma unroll
            for (int r = 0; r < 4; ++r) {
                int row = w * 16 + quad * 4 + r;
                T[o * 72 + row] = f2h_bits(acc[nt][r] + bias);
            }
        }
    }
    __syncthreads();
    #pragma unroll
    for (int i = 0; i < 4; ++i) {
        int idx = tid + i * 256;
        int d = idx >> 3, c8 = (idx & 7) * 8;
        uint4 dv = *(uint4*)&T[d * 72 + c8];
        *(uint4*)&vo[(((size_t)bi * H_ + h) * D_ + d) * S_ + sbase + c8] = dv;
    }
}

// ---------------- Flash attention, barrier-free ----------------
// grid: 512 1-D (XCD swizzle: h = bid&7), block 256 (4 waves × 32 Q-rows).
// K and V^T frags read DIRECTLY from global (L2-resident per XCD).
// LDS: only the wave-private P/Q round-trip buffer [128][136] = 34.8 KB.
// ZERO __syncthreads: no barrier vmcnt drains; loads overlap compute per-use.
__global__ __launch_bounds__(256, 2) void attn(
    const float* __restrict__ seq, const float* __restrict__ Wq,
    const float* __restrict__ bq,
    const ushort* __restrict__ kg, const ushort* __restrict__ vtg,
    float* __restrict__ out)
{
    constexpr int PS = 136;
    __shared__ alignas(16) ushort Plds[128 * PS];   // 34816 B; rows wave-private

    const int bid = blockIdx.x;
    const int h  = bid & 7;                  // XCD swizzle: head h -> XCD h
    const int m0 = ((bid >> 3) & 15) * 128;
    const int bi = bid >> 7;
    const int bh = bi * H_ + h;
    const int tid = threadIdx.x, lane = tid & 63, w = tid >> 6;
    const int l16 = lane & 15, quad = lane >> 4;
    const size_t baseK = (size_t)bh * S_ * D_;
    const size_t baseV = (size_t)bh * D_ * S_;
    const float qscale = 0.35355339059327373f * 1.4426950408889634f; // 1/sqrt(8)*log2e
    const int qq_r = (l16 >> 2) & 3;   // read-side swizzle for P/Q frag rows

    // ---- Phase 0: Q tile = X Wq^T + bq (scaled); LDS rows are wave-private ----
    {
        f16x8 xa[2][4];
        #pragma unroll
        for (int mt = 0; mt < 2; ++mt)
            #pragma unroll
            for (int ks = 0; ks < 4; ++ks)
                xa[mt][ks] = pack8(&seq[((size_t)bi * S_ + m0 + w * 32 + mt * 16 + l16) * E_
                                        + h * D_ + ks * 32 + quad * 8]);
        f32x4 qacc[2][8];
        #pragma unroll
        for (int mt = 0; mt < 2; ++mt)
            #pragma unroll
            for (int nt = 0; nt < 8; ++nt) { f32x4 z = {0.f,0.f,0.f,0.f}; qacc[mt][nt] = z; }
        const float* W = Wq + (size_t)h * D_ * D_;
        #pragma unroll
        for (int ks = 0; ks < 4; ++ks)
            #pragma unroll
            for (int nt = 0; nt < 8; ++nt) {
                f16x8 bfr = pack8(&W[(size_t)(nt * 16 + l16) * D_ + ks * 32 + quad * 8]);
                #pragma unroll
                for (int mt = 0; mt < 2; ++mt)
                    qacc[mt][nt] = __builtin_amdgcn_mfma_f32_16x16x32_f16(
                        xa[mt][ks], bfr, qacc[mt][nt], 0, 0, 0);
            }
        #pragma unroll
        for (int nt = 0; nt < 8; ++nt) {
            int o = nt * 16 + l16;
            float bias = bq[h * D_ + o];
            #pragma unroll
            for (int mt = 0; mt < 2; ++mt)
                #pragma unroll
                for (int r = 0; r < 4; ++r) {
                    int row = w * 32 + mt * 16 + quad * 4 + r;
                    Plds[row * PS + (o ^ (quad << 3))] =
                        f2h_bits((qacc[mt][nt][r] + bias) * qscale);
                }
        }
    }
    // same-wave LDS RAW: compiler inserts lgkmcnt wait; no barrier needed
    f16x8 qf[2][4];
    #pragma unroll
    for (int mt = 0; mt < 2; ++mt)
        #pragma unroll
        for (int ks = 0; ks < 4; ++ks)
            qf[mt][ks] = *(const f16x8*)&Plds[(w * 32 + mt * 16 + l16) * PS
                                              + ks * 32 + ((quad ^ qq_r) << 3)];

    f32x4 o_acc[2][8];
    #pragma unroll
    for (int mt = 0; mt < 2; ++mt)
        #pragma unroll
        for (int nt = 0; nt < 8; ++nt) { f32x4 z = {0.f,0.f,0.f,0.f}; o_acc[mt][nt] = z; }
    float m_prev[2][4], l_lane[2][4];
    #pragma unroll
    for (int mt = 0; mt < 2; ++mt)
        #pragma unroll
        for (int r = 0; r < 4; ++r) { m_prev[mt][r] = -1e30f; l_lane[mt][r] = 0.f; }

    for (int j = 0; j < S_ / 128; ++j) {
        const int n0 = j * 128;

        // S = Q K^T, kf frags direct from global (L2)
        f32x4 sacc[2][8];
        #pragma unroll
        for (int mt = 0; mt < 2; ++mt)
            #pragma unroll
            for (int nt = 0; nt < 8; ++nt) { f32x4 z = {0.f,0.f,0.f,0.f}; sacc[mt][nt] = z; }
        #pragma unroll
        for (int ks = 0; ks < 4; ++ks)
            #pragma unroll
            for (int nt = 0; nt < 8; ++nt) {
                f16x8 kf = *(const f16x8*)&kg[baseK + (size_t)(n0 + nt * 16 + l16) * D_
                                              + ks * 32 + quad * 8];
                #pragma unroll
                for (int mt = 0; mt < 2; ++mt)
                    sacc[mt][nt] = __builtin_amdgcn_mfma_f32_16x16x32_f16(
                        qf[mt][ks], kf, sacc[mt][nt], 0, 0, 0);
            }

        // online softmax; p packed into sacc as fp16 bits
        #pragma unroll
        for (int mt = 0; mt < 2; ++mt)
            #pragma unroll
            for (int r = 0; r < 4; ++r) {
                float mx = sacc[mt][0][r];
                #pragma unroll
                for (int nt = 1; nt < 8; ++nt) mx = fmaxf(mx, sacc[mt][nt][r]);
                #pragma unroll
                for (int d = 1; d < 16; d <<= 1)
                    mx = fmaxf(mx, __shfl_xor(mx, d));
                float mnew  = fmaxf(m_prev[mt][r], mx);
                float alpha = exp2f(m_prev[mt][r] - mnew);
                m_prev[mt][r] = mnew;
                float sumr = 0.f;
                #pragma unroll
                for (int nt = 0; nt < 8; ++nt) {
                    float p = exp2f(sacc[mt][nt][r] - mnew);
                    sumr += p;
                    sacc[mt][nt][r] = __uint_as_float((unsigned)f2h_bits(p));
                }
                l_lane[mt][r] = l_lane[mt][r] * alpha + sumr;
                #pragma unroll
                for (int nt = 0; nt < 8; ++nt)
                    o_acc[mt][nt][r] *= alpha;
            }

        // P writes (swizzled, wave-private rows) — no barrier
        #pragma unroll
        for (int mt = 0; mt < 2; ++mt)
            #pragma unroll
            for (int r = 0; r < 4; ++r) {
                int row = w * 32 + mt * 16 + quad * 4 + r;
                #pragma unroll
                for (int nt = 0; nt < 8; ++nt) {
                    int col = nt * 16 + l16;
                    Plds[row * PS + (col ^ (quad << 3))] =
                        (ushort)__float_as_uint(sacc[mt][nt][r]);
                }
            }

        // O += P V, vf frags direct from transposed global V
        #pragma unroll
        for (int ks = 0; ks < 4; ++ks) {
            f16x8 pa[2];
            #pragma unroll
            for (int mt = 0; mt < 2; ++mt)
                pa[mt] = *(const f16x8*)&Plds[(w * 32 + mt * 16 + l16) * PS
                                              + ks * 32 + ((quad ^ qq_r) << 3)];
            #pragma unroll
            for (int nt = 0; nt < 8; ++nt) {
                f16x8 vf = *(const f16x8*)&vtg[baseV + (size_t)(nt * 16 + l16) * S_
                                               + n0 + ks * 32 + quad * 8];
                #pragma unroll
                for (int mt = 0; mt < 2; ++mt)
                    o_acc[mt][nt] = __builtin_amdgcn_mfma_f32_16x16x32_f16(
                        pa[mt], vf, o_acc[mt][nt], 0, 0, 0);
            }
        }
    }

    // epilogue: reduce l across 16-lane row group, O/l, write fp32 [B,S,E]
    #pragma unroll
    for (int mt = 0; mt < 2; ++mt)
        #pragma unroll
        for (int r = 0; r < 4; ++r) {
            float l = l_lane[mt][r];
            #pragma unroll
            for (int d = 1; d < 16; d <<= 1)
                l += __shfl_xor(l, d);
            float rinv = 1.0f / l;
            int srow = m0 + w * 32 + mt * 16 + quad * 4 + r;
            #pragma unroll
            for (int nt = 0; nt < 8; ++nt) {
                int col = nt * 16 + l16;
                out[((size_t)bi * S_ + srow) * E_ + h * D_ + col] =
                    o_acc[mt][nt][r] * rinv;
            }
        }
}

extern "C" void kernel_launch(void* const* d_in, const int* in_sizes, int n_in,
                              void* d_out, int out_size, void* d_ws, size_t ws_size,
                              hipStream_t stream) {
    const float* seq = (const float*)d_in[0];
    const float* Wq  = (const float*)d_in[1];
    const float* Wk  = (const float*)d_in[2];
    const float* Wv  = (const float*)d_in[3];
    const float* bq  = (const float*)d_in[4];
    const float* bk  = (const float*)d_in[5];
    const float* bv  = (const float*)d_in[6];

    const size_t per = (size_t)B_ * H_ * S_ * D_;      // 8M elements
    if (ws_size < 2 * per * sizeof(ushort)) return;    // need 32 MB
    ushort* kws  = (ushort*)d_ws;          // [B,H,S,D]
    ushort* vtws = kws + per;              // [B,H,D,S] (transposed)

    kv_proj<<<dim3(B_ * S_ / 64, H_), 256, 0, stream>>>(
        seq, Wk, Wv, bk, bv, kws, vtws);
    attn<<<512, 256, 0, stream>>>(
        seq, Wq, bq, kws, vtws, (float*)d_out);
}

// Round 8
// 339.487 us; speedup vs baseline: 1.2965x; 1.2965x over previous
//
#include <hip/hip_runtime.h>
#include <hip/hip_bf16.h>

#define B_ 4
#define S_ 2048
#define E_ 1024
#define H_ 8
#define D_ 128

using f16x8 = __attribute__((ext_vector_type(8))) _Float16;
using f32x4 = __attribute__((ext_vector_type(4))) float;

__device__ __forceinline__ ushort f2h_bits(float f) {
    union { _Float16 h; ushort u; } cv; cv.h = (_Float16)f; return cv.u;
}
__device__ __forceinline__ f16x8 pack8(const float* __restrict__ p) {
    float4 f0 = *(const float4*)p;
    float4 f1 = *(const float4*)(p + 4);
    f16x8 r;
    r[0] = (_Float16)f0.x; r[1] = (_Float16)f0.y;
    r[2] = (_Float16)f0.z; r[3] = (_Float16)f0.w;
    r[4] = (_Float16)f1.x; r[5] = (_Float16)f1.y;
    r[6] = (_Float16)f1.z; r[7] = (_Float16)f1.w;
    return r;
}

// async global->LDS, 16B per lane: LDS dest = lds_ptr + lane*16
#define GLD_LDS(gp, lp)                                                      \
    __builtin_amdgcn_global_load_lds(                                        \
        (const __attribute__((address_space(1))) void*)(gp),                 \
        (__attribute__((address_space(3))) void*)(lp), 16, 0, 0)

// Swizzled image layouts (fp16, unpadded 128-col rows):
//   phys_elem(row, col) = row*128 + (((col>>3) ^ (row&7))<<3) + (col&7)
// K' ws:  [b][h][s][.]   row key = s&7,  col = d
// V' ws:  [b][h][tile][d][.] (tile = s/128), row key = d&7, col = s_local

// ---------------- K/V projection ----------------
// grid (B*S/128, H) = 512 blocks, 256 thr, BM=128.
// W staged fp32->fp16 into LDS coalesced once per pass; B-frags via ds_read_b128.
__global__ __launch_bounds__(256, 2) void kv_proj(
    const float* __restrict__ seq,
    const float* __restrict__ Wk, const float* __restrict__ Wv,
    const float* __restrict__ bk, const float* __restrict__ bv,
    ushort* __restrict__ ko, ushort* __restrict__ vo)
{
    __shared__ alignas(16) ushort Ws[128 * 128];    // 32 KB, swizzled W image
    __shared__ alignas(16) ushort Timg[128 * 128];  // 32 KB, output tile image
    const int m0 = blockIdx.x * 128, h = blockIdx.y;
    const int tid = threadIdx.x, lane = tid & 63, w = tid >> 6;
    const int l16 = lane & 15, quad = lane >> 4;
    const int bh = ((m0 >> 11) * H_) + h;          // batch fixed per block
    const int sbase = m0 & (S_ - 1);
    const int tile = sbase >> 7;

    // A-frags direct from global fp32 (once per block)
    f16x8 xa[2][4];
    #pragma unroll
    for (int mt = 0; mt < 2; ++mt)
        #pragma unroll
        for (int ks = 0; ks < 4; ++ks)
            xa[mt][ks] = pack8(&seq[(size_t)(m0 + w * 32 + mt * 16 + l16) * E_
                                    + h * D_ + ks * 32 + quad * 8]);

    // ---- stage Wk -> Ws (swizzled) ----
    {
        const float* W = Wk + (size_t)h * D_ * D_;
        #pragma unroll
        for (int i = 0; i < 8; ++i) {
            int idx = tid + i * 256;
            int o = idx >> 4, c8 = (idx & 15) * 8;
            f16x8 d = pack8(&W[(size_t)o * D_ + c8]);
            *(f16x8*)&Ws[o * 128 + ((((c8 >> 3) ^ (o & 7))) << 3)] = d;
        }
    }
    __syncthreads();

    // ---- K = X Wk^T : MFMA from LDS frags ----
    {
        f32x4 acc[2][8];
        #pragma unroll
        for (int mt = 0; mt < 2; ++mt)
            #pragma unroll
            for (int nt = 0; nt < 8; ++nt) { f32x4 z = {0.f,0.f,0.f,0.f}; acc[mt][nt] = z; }
        #pragma unroll
        for (int ks = 0; ks < 4; ++ks)
            #pragma unroll
            for (int nt = 0; nt < 8; ++nt) {
                f16x8 bfr = *(const f16x8*)&Ws[(nt * 16 + l16) * 128
                                               + (((ks * 4 + quad) ^ (l16 & 7)) << 3)];
                #pragma unroll
                for (int mt = 0; mt < 2; ++mt)
                    acc[mt][nt] = __builtin_amdgcn_mfma_f32_16x16x32_f16(
                        xa[mt][ks], bfr, acc[mt][nt], 0, 0, 0);
            }
        #pragma unroll
        for (int nt = 0; nt < 8; ++nt) {
            int o = nt * 16 + l16;
            float bias = bk[h * D_ + o];
            #pragma unroll
            for (int mt = 0; mt < 2; ++mt)
                #pragma unroll
                for (int r = 0; r < 4; ++r) {
                    int row = w * 32 + mt * 16 + quad * 4 + r;   // s_local
                    Timg[row * 128 + ((((o >> 3) ^ (row & 7))) << 3) + (o & 7)] =
                        f2h_bits(acc[mt][nt][r] + bias);
                }
        }
    }
    __syncthreads();   // all MFMAs (Ws reads) + Timg writes done

    // copy out K image (linear) and stage Wv
    #pragma unroll
    for (int i = 0; i < 8; ++i) {
        int idx = tid + i * 256;
        int row = idx >> 4, c8 = (idx & 15) * 8;
        *(uint4*)&ko[((size_t)bh * S_ + sbase + row) * D_ + c8] =
            *(uint4*)&Timg[row * 128 + c8];
    }
    {
        const float* W = Wv + (size_t)h * D_ * D_;
        #pragma unroll
        for (int i = 0; i < 8; ++i) {
            int idx = tid + i * 256;
            int o = idx >> 4, c8 = (idx & 15) * 8;
            f16x8 d = pack8(&W[(size_t)o * D_ + c8]);
            *(f16x8*)&Ws[o * 128 + ((((c8 >> 3) ^ (o & 7))) << 3)] = d;
        }
    }
    __syncthreads();   // K copyout read + Wv staged

    // ---- V = X Wv^T, write transposed image [d][s_local] ----
    {
        f32x4 acc[2][8];
        #pragma unroll
        for (int mt = 0; mt < 2; ++mt)
            #pragma unroll
            for (int nt = 0; nt < 8; ++nt) { f32x4 z = {0.f,0.f,0.f,0.f}; acc[mt][nt] = z; }
        #pragma unroll
        for (int ks = 0; ks < 4; ++ks)
            #pragma unroll
            for (int nt = 0; nt < 8; ++nt) {
                f16x8 bfr = *(const f16x8*)&Ws[(nt * 16 + l16) * 128
                                               + (((ks * 4 + quad) ^ (l16 & 7)) << 3)];
                #pragma unroll
                for (int mt = 0; mt < 2; ++mt)
                    acc[mt][nt] = __builtin_amdgcn_mfma_f32_16x16x32_f16(
                        xa[mt][ks], bfr, acc[mt][nt], 0, 0, 0);
            }
        #pragma unroll
        for (int nt = 0; nt < 8; ++nt) {
            int o = nt * 16 + l16;                               // d
            float bias = bv[h * D_ + o];
            #pragma unroll
            for (int mt = 0; mt < 2; ++mt)
                #pragma unroll
                for (int r = 0; r < 4; ++r) {
                    int row = w * 32 + mt * 16 + quad * 4 + r;   // s_local
                    Timg[o * 128 + ((((row >> 3) ^ (o & 7))) << 3) + (row & 7)] =
                        f2h_bits(acc[mt][nt][r] + bias);
                }
        }
    }
    __syncthreads();
    // copy out V image (linear, tile-major)
    #pragma unroll
    for (int i = 0; i < 8; ++i) {
        int idx = tid + i * 256;
        int d = idx >> 4, c8 = (idx & 15) * 8;
        *(uint4*)&vo[(((size_t)bh * 16 + tile) * 128 + d) * 128 + c8] =
            *(uint4*)&Timg[d * 128 + c8];
    }
}

// ---------------- Flash attention ----------------
// grid (16, 8, 4), block 256 (4 waves x 32 Q-rows). BN=128.
// K/V staged via global_load_lds from pre-swizzled ws; P aliases K region.
__global__ __launch_bounds__(256, 2) void attn(
    const float* __restrict__ seq, const float* __restrict__ Wq,
    const float* __restrict__ bq,
    const ushort* __restrict__ kg, const ushort* __restrict__ vtg,
    float* __restrict__ out)
{
    __shared__ alignas(16) ushort KP[128 * 128];    // 32 KB: K tile; Q then P alias
    __shared__ alignas(16) ushort Vimg[128 * 128];  // 32 KB: V^T tile

    const int m0 = blockIdx.x * 128;
    const int h = blockIdx.y, bi = blockIdx.z;
    const int bh = bi * H_ + h;
    const int tid = threadIdx.x, lane = tid & 63, w = tid >> 6;
    const int l16 = lane & 15, quad = lane >> 4;
    const size_t baseK = (size_t)bh * S_ * D_;
    const float qscale = 0.35355339059327373f * 1.4426950408889634f; // 1/sqrt(8)*log2e

    // ---- Phase 0: Q tile = X Wq^T + bq (scaled) via KP (wave-private rows) ----
    {
        f16x8 xa[2][4];
        #pragma unroll
        for (int mt = 0; mt < 2; ++mt)
            #pragma unroll
            for (int ks = 0; ks < 4; ++ks)
                xa[mt][ks] = pack8(&seq[((size_t)bi * S_ + m0 + w * 32 + mt * 16 + l16) * E_
                                        + h * D_ + ks * 32 + quad * 8]);
        f32x4 qacc[2][8];
        #pragma unroll
        for (int mt = 0; mt < 2; ++mt)
            #pragma unroll
            for (int nt = 0; nt < 8; ++nt) { f32x4 z = {0.f,0.f,0.f,0.f}; qacc[mt][nt] = z; }
        const float* W = Wq + (size_t)h * D_ * D_;
        #pragma unroll
        for (int ks = 0; ks < 4; ++ks)
            #pragma unroll
            for (int nt = 0; nt < 8; ++nt) {
                f16x8 bfr = pack8(&W[(size_t)(nt * 16 + l16) * D_ + ks * 32 + quad * 8]);
                #pragma unroll
                for (int mt = 0; mt < 2; ++mt)
                    qacc[mt][nt] = __builtin_amdgcn_mfma_f32_16x16x32_f16(
                        xa[mt][ks], bfr, qacc[mt][nt], 0, 0, 0);
            }
        #pragma unroll
        for (int nt = 0; nt < 8; ++nt) {
            int o = nt * 16 + l16;
            float bias = bq[h * D_ + o];
            #pragma unroll
            for (int mt = 0; mt < 2; ++mt)
                #pragma unroll
                for (int r = 0; r < 4; ++r) {
                    int row = w * 32 + mt * 16 + quad * 4 + r;
                    KP[row * 128 + ((((o >> 3) ^ (row & 7))) << 3) + (o & 7)] =
                        f2h_bits((qacc[mt][nt][r] + bias) * qscale);
                }
        }
    }
    // same-wave RAW via lgkmcnt; rows wave-private
    f16x8 qf[2][4];
    #pragma unroll
    for (int mt = 0; mt < 2; ++mt)
        #pragma unroll
        for (int ks = 0; ks < 4; ++ks)
            qf[mt][ks] = *(const f16x8*)&KP[(w * 32 + mt * 16 + l16) * 128
                                            + (((ks * 4 + quad) ^ (l16 & 7)) << 3)];

    f32x4 o_acc[2][8];
    #pragma unroll
    for (int mt = 0; mt < 2; ++mt)
        #pragma unroll
        for (int nt = 0; nt < 8; ++nt) { f32x4 z = {0.f,0.f,0.f,0.f}; o_acc[mt][nt] = z; }
    float m_prev[2][4], l_lane[2][4];
    #pragma unroll
    for (int mt = 0; mt < 2; ++mt)
        #pragma unroll
        for (int r = 0; r < 4; ++r) { m_prev[mt][r] = -1e30f; l_lane[mt][r] = 0.f; }

    for (int j = 0; j < S_ / 128; ++j) {
        const int n0 = j * 128;
        __syncthreads();   // A: prior P/V reads done before restage
        // async stage K rows w*32..+31 (linear image copy, 8 x 1KB)
        #pragma unroll
        for (int t = 0; t < 8; ++t)
            GLD_LDS(kg + baseK + (size_t)(n0 + w * 32 + t * 4) * 128 + lane * 8,
                    &KP[(w * 32 + t * 4) * 128]);
        // async stage V^T rows (d) w*32..+31 from tile-major ws
        const size_t baseV = ((size_t)bh * 16 + j) * 128 * 128;
        #pragma unroll
        for (int t = 0; t < 8; ++t)
            GLD_LDS(vtg + baseV + (size_t)(w * 32 + t * 4) * 128 + lane * 8,
                    &Vimg[(w * 32 + t * 4) * 128]);
        __syncthreads();   // B: staging complete (vmcnt drain)

        // S = Q K^T (wave: [32 x 128])
        f32x4 sacc[2][8];
        #pragma unroll
        for (int mt = 0; mt < 2; ++mt)
            #pragma unroll
            for (int nt = 0; nt < 8; ++nt) { f32x4 z = {0.f,0.f,0.f,0.f}; sacc[mt][nt] = z; }
        #pragma unroll
        for (int ks = 0; ks < 4; ++ks)
            #pragma unroll
            for (int nt = 0; nt < 8; ++nt) {
                f16x8 kf = *(const f16x8*)&KP[(nt * 16 + l16) * 128
                                              + (((ks * 4 + quad) ^ (l16 & 7)) << 3)];
                #pragma unroll
                for (int mt = 0; mt < 2; ++mt)
                    sacc[mt][nt] = __builtin_amdgcn_mfma_f32_16x16x32_f16(
                        qf[mt][ks], kf, sacc[mt][nt], 0, 0, 0);
            }

        // online softmax; p packed into sacc as fp16 bits
        #pragma unroll
        for (int mt = 0; mt < 2; ++mt)
            #pragma unroll
            for (int r = 0; r < 4; ++r) {
                float mx = sacc[mt][0][r];
                #pragma unroll
                for (int nt = 1; nt < 8; ++nt) mx = fmaxf(mx, sacc[mt][nt][r]);
                #pragma unroll
                for (int d = 1; d < 16; d <<= 1)
                    mx = fmaxf(mx, __shfl_xor(mx, d));
                float mnew  = fmaxf(m_prev[mt][r], mx);
                float alpha = exp2f(m_prev[mt][r] - mnew);
                m_prev[mt][r] = mnew;
                float sumr = 0.f;
                #pragma unroll
                for (int nt = 0; nt < 8; ++nt) {
                    float p = exp2f(sacc[mt][nt][r] - mnew);
                    sumr += p;
                    sacc[mt][nt][r] = __uint_as_float((unsigned)f2h_bits(p));
                }
                l_lane[mt][r] = l_lane[mt][r] * alpha + sumr;
                #pragma unroll
                for (int nt = 0; nt < 8; ++nt)
                    o_acc[mt][nt][r] *= alpha;
            }

        __syncthreads();   // C: all waves done reading K frags; P may overwrite
        // P writes (swizzled image, wave-private rows)
        #pragma unroll
        for (int mt = 0; mt < 2; ++mt)
            #pragma unroll
            for (int r = 0; r < 4; ++r) {
                int row = w * 32 + mt * 16 + quad * 4 + r;
                #pragma unroll
                for (int nt = 0; nt < 8; ++nt) {
                    int col = nt * 16 + l16;
                    KP[row * 128 + ((((col >> 3) ^ (row & 7))) << 3) + (col & 7)] =
                        (ushort)__float_as_uint(sacc[mt][nt][r]);
                }
            }

        // O += P V (pa from own rows; same-wave DS ordering)
        #pragma unroll
        for (int ks = 0; ks < 4; ++ks) {
            f16x8 pa[2];
            #pragma unroll
            for (int mt = 0; mt < 2; ++mt)
                pa[mt] = *(const f16x8*)&KP[(w * 32 + mt * 16 + l16) * 128
                                            + (((ks * 4 + quad) ^ (l16 & 7)) << 3)];
            #pragma unroll
            for (int nt = 0; nt < 8; ++nt) {
                f16x8 vf = *(const f16x8*)&Vimg[(nt * 16 + l16) * 128
                                                + (((ks * 4 + quad) ^ (l16 & 7)) << 3)];
                #pragma unroll
                for (int mt = 0; mt < 2; ++mt)
                    o_acc[mt][nt] = __builtin_amdgcn_mfma_f32_16x16x32_f16(
                        pa[mt], vf, o_acc[mt][nt], 0, 0, 0);
            }
        }
    }

    // epilogue: reduce l across 16-lane row group, O/l, write fp32 [B,S,E]
    #pragma unroll
    for (int mt = 0; mt < 2; ++mt)
        #pragma unroll
        for (int r = 0; r < 4; ++r) {
            float l = l_lane[mt][r];
            #pragma unroll
            for (int d = 1; d < 16; d <<= 1)
                l += __shfl_xor(l, d);
            float rinv = 1.0f / l;
            int srow = m0 + w * 32 + mt * 16 + quad * 4 + r;
            #pragma unroll
            for (int nt = 0; nt < 8; ++nt) {
                int col = nt * 16 + l16;
                out[((size_t)bi * S_ + srow) * E_ + h * D_ + col] =
                    o_acc[mt][nt][r] * rinv;
            }
        }
}

extern "C" void kernel_launch(void* const* d_in, const int* in_sizes, int n_in,
                              void* d_out, int out_size, void* d_ws, size_t ws_size,
                              hipStream_t stream) {
    const float* seq = (const float*)d_in[0];
    const float* Wq  = (const float*)d_in[1];
    const float* Wk  = (const float*)d_in[2];
    const float* Wv  = (const float*)d_in[3];
    const float* bq  = (const float*)d_in[4];
    const float* bk  = (const float*)d_in[5];
    const float* bv  = (const float*)d_in[6];

    const size_t per = (size_t)B_ * H_ * S_ * D_;      // 8M elements
    if (ws_size < 2 * per * sizeof(ushort)) return;    // need 32 MB
    ushort* kws  = (ushort*)d_ws;          // K' swizzled [B,H,S,128]
    ushort* vtws = kws + per;              // V' swizzled tile-major [B,H,16,128,128]

    kv_proj<<<dim3(B_ * S_ / 128, H_), 256, 0, stream>>>(
        seq, Wk, Wv, bk, bv, kws, vtws);
    attn<<<dim3(S_ / 128, H_, B_), 256, 0, stream>>>(
        seq, Wq, bq, kws, vtws, (float*)d_out);
}